// Round 3
// baseline (458.785 us; speedup 1.0000x reference)
//
#include <hip/hip_runtime.h>
#include <math.h>

#define ALPHA 0.5f
#define BETA 0.9f
#define Bsz 512
#define Tsz 512
#define Dsz 256
#define NCHUNK 4
#define CROWS (Tsz / NCHUNK)   // 128 t-rows per chunk block

__device__ __forceinline__ float wave_reduce_sum(float v) {
    v += __shfl_xor(v, 32, 64);
    v += __shfl_xor(v, 16, 64);
    v += __shfl_xor(v, 8, 64);
    v += __shfl_xor(v, 4, 64);
    v += __shfl_xor(v, 2, 64);
    v += __shfl_xor(v, 1, 64);
    return v;
}

__device__ __forceinline__ float wave_reduce_max(float v) {
    v = fmaxf(v, __shfl_xor(v, 32, 64));
    v = fmaxf(v, __shfl_xor(v, 16, 64));
    v = fmaxf(v, __shfl_xor(v, 8, 64));
    v = fmaxf(v, __shfl_xor(v, 4, 64));
    v = fmaxf(v, __shfl_xor(v, 2, 64));
    v = fmaxf(v, __shfl_xor(v, 1, 64));
    return v;
}

// ---------- kA1: partial mean-pool over 128 t-rows ----------
__global__ __launch_bounds__(256) void kA1(const float* __restrict__ x,
                                           const float* __restrict__ ts,
                                           const unsigned char* __restrict__ pad,
                                           float* __restrict__ qpart,
                                           float* __restrict__ cntp,
                                           float* __restrict__ tmaxp) {
    const int idx = blockIdx.x;             // b*NCHUNK + chunk
    const int b = idx >> 2, chunk = idx & 3;
    const int tid = threadIdx.x;
    const int w = tid >> 6, lane = tid & 63;
    const int t0 = chunk * CROWS;

    __shared__ float validS[CROWS];
    __shared__ float part[4][Dsz];
    __shared__ float red[8];

    float lmax = -3e38f, lcnt = 0.f;
    if (tid < CROWS) {
        bool v = (pad[(size_t)b * Tsz + t0 + tid] == 0);
        float tv = ts[(size_t)b * Tsz + t0 + tid];
        validS[tid] = v ? 1.f : 0.f;
        if (v) { lmax = tv; lcnt = 1.f; }
    }
    lmax = wave_reduce_max(lmax);
    lcnt = wave_reduce_sum(lcnt);
    if (lane == 0) { red[w] = lmax; red[4 + w] = lcnt; }
    __syncthreads();

    // wave w owns local rows [w*32, w*32+32); 4-row ILP
    const float* xb = x + (size_t)b * Tsz * Dsz;
    float4 a0 = make_float4(0.f, 0.f, 0.f, 0.f);
    float4 a1 = a0, a2 = a0, a3 = a0;
    const int lb = w * 32;
    for (int i = 0; i < 32; i += 4) {
        const int lt = lb + i;
        const size_t g = (size_t)(t0 + lt) * Dsz + lane * 4;
        float4 x0 = *(const float4*)(xb + g);
        float4 x1 = *(const float4*)(xb + g + Dsz);
        float4 x2 = *(const float4*)(xb + g + 2 * Dsz);
        float4 x3 = *(const float4*)(xb + g + 3 * Dsz);
        const float v0 = validS[lt], v1 = validS[lt + 1], v2 = validS[lt + 2], v3 = validS[lt + 3];
        a0.x += v0 * x0.x; a0.y += v0 * x0.y; a0.z += v0 * x0.z; a0.w += v0 * x0.w;
        a1.x += v1 * x1.x; a1.y += v1 * x1.y; a1.z += v1 * x1.z; a1.w += v1 * x1.w;
        a2.x += v2 * x2.x; a2.y += v2 * x2.y; a2.z += v2 * x2.z; a2.w += v2 * x2.w;
        a3.x += v3 * x3.x; a3.y += v3 * x3.y; a3.z += v3 * x3.z; a3.w += v3 * x3.w;
    }
    part[w][lane * 4 + 0] = (a0.x + a1.x) + (a2.x + a3.x);
    part[w][lane * 4 + 1] = (a0.y + a1.y) + (a2.y + a3.y);
    part[w][lane * 4 + 2] = (a0.z + a1.z) + (a2.z + a3.z);
    part[w][lane * 4 + 3] = (a0.w + a1.w) + (a2.w + a3.w);
    __syncthreads();
    qpart[(size_t)idx * Dsz + tid] = (part[0][tid] + part[1][tid]) + (part[2][tid] + part[3][tid]);
    if (tid == 0) {
        tmaxp[idx] = fmaxf(fmaxf(red[0], red[1]), fmaxf(red[2], red[3]));
        cntp[idx] = (red[4] + red[5]) + (red[6] + red[7]);
    }
}

// ---------- kA2: combine partials -> q -> Q -> Qk (pre-scaled) ----------
__global__ __launch_bounds__(256) void kA2(const float* __restrict__ qpart,
                                           const float* __restrict__ cntp,
                                           const float* __restrict__ tmaxp,
                                           const float* __restrict__ WQ,
                                           const float* __restrict__ WK,
                                           float* __restrict__ qk,
                                           float* __restrict__ tmax_out) {
    const int b = blockIdx.x;
    const int tid = threadIdx.x;
    __shared__ float qS[Dsz];
    __shared__ float QS[Dsz];
    __shared__ float cntS;

    if (tid == 0) {
        float tm = fmaxf(fmaxf(tmaxp[b * 4], tmaxp[b * 4 + 1]),
                         fmaxf(tmaxp[b * 4 + 2], tmaxp[b * 4 + 3]));
        cntS = fmaxf(cntp[b * 4] + cntp[b * 4 + 1] + cntp[b * 4 + 2] + cntp[b * 4 + 3], 1.f);
        tmax_out[b] = tm;
    }
    __syncthreads();
    qS[tid] = ((qpart[(size_t)(b * 4 + 0) * Dsz + tid] + qpart[(size_t)(b * 4 + 1) * Dsz + tid]) +
               (qpart[(size_t)(b * 4 + 2) * Dsz + tid] + qpart[(size_t)(b * 4 + 3) * Dsz + tid])) / cntS;
    __syncthreads();

    float Qi = 0.f;
    const float* wqrow = WQ + (size_t)tid * Dsz;
    #pragma unroll 4
    for (int d4 = 0; d4 < Dsz; d4 += 4) {
        float4 wv = *(const float4*)(wqrow + d4);
        Qi += wv.x * qS[d4] + wv.y * qS[d4 + 1] + wv.z * qS[d4 + 2] + wv.w * qS[d4 + 3];
    }
    QS[tid] = Qi;
    __syncthreads();

    float v = 0.f;
    #pragma unroll 8
    for (int e = 0; e < Dsz; ++e) {
        v += QS[e] * WK[(size_t)e * Dsz + tid];
    }
    qk[(size_t)b * Dsz + tid] = v * 0.0625f;   // 1/sqrt(256)
}

// ---------- kB1: partial streaming scores/exp/weighted-sum over 128 t-rows ----------
__global__ __launch_bounds__(256) void kB1(const float* __restrict__ x,
                                           const float* __restrict__ ts,
                                           const unsigned char* __restrict__ pad,
                                           const float* __restrict__ qk,
                                           const float* __restrict__ tmax_in,
                                           float* __restrict__ accp,
                                           float* __restrict__ Ep,
                                           float* __restrict__ Gp) {
    const int idx = blockIdx.x;             // b*NCHUNK + chunk
    const int b = idx >> 2, chunk = idx & 3;
    const int tid = threadIdx.x;
    const int w = tid >> 6, lane = tid & 63;
    const int t0 = chunk * CROWS;

    __shared__ float lamS[CROWS];
    __shared__ float okS[CROWS];
    __shared__ float accS[4][Dsz];
    __shared__ float EGS[8];

    const float tmax = tmax_in[b];
    if (tid < CROWS) {
        bool valid = (pad[(size_t)b * Tsz + t0 + tid] == 0);
        float dt = fmaxf(tmax - ts[(size_t)b * Tsz + t0 + tid], 0.f) * (1.f / 86400.f);
        lamS[tid] = valid ? __expf(-ALPHA * dt) : 0.f;
        okS[tid] = valid ? 1.f : 0.f;
    }
    __syncthreads();

    const float4 qk4 = *(const float4*)(qk + (size_t)b * Dsz + lane * 4);
    const float* xb = x + (size_t)b * Tsz * Dsz;
    float4 acc = make_float4(0.f, 0.f, 0.f, 0.f);
    float E = 0.f, G = 0.f;
    const int lb = w * 32;
    for (int i = 0; i < 32; i += 4) {
        const int lt = lb + i;
        const size_t g = (size_t)(t0 + lt) * Dsz + lane * 4;
        float4 x0 = *(const float4*)(xb + g);
        float4 x1 = *(const float4*)(xb + g + Dsz);
        float4 x2 = *(const float4*)(xb + g + 2 * Dsz);
        float4 x3 = *(const float4*)(xb + g + 3 * Dsz);
        float s0 = qk4.x * x0.x + qk4.y * x0.y + qk4.z * x0.z + qk4.w * x0.w;
        float s1 = qk4.x * x1.x + qk4.y * x1.y + qk4.z * x1.z + qk4.w * x1.w;
        float s2 = qk4.x * x2.x + qk4.y * x2.y + qk4.z * x2.z + qk4.w * x2.w;
        float s3 = qk4.x * x3.x + qk4.y * x3.y + qk4.z * x3.z + qk4.w * x3.w;
        #pragma unroll
        for (int off = 32; off >= 1; off >>= 1) {
            s0 += __shfl_xor(s0, off, 64);
            s1 += __shfl_xor(s1, off, 64);
            s2 += __shfl_xor(s2, off, 64);
            s3 += __shfl_xor(s3, off, 64);
        }
        float e0 = okS[lt + 0] * __expf(s0);
        float e1 = okS[lt + 1] * __expf(s1);
        float e2 = okS[lt + 2] * __expf(s2);
        float e3 = okS[lt + 3] * __expf(s3);
        float g0 = lamS[lt + 0] * e0;
        float g1 = lamS[lt + 1] * e1;
        float g2 = lamS[lt + 2] * e2;
        float g3 = lamS[lt + 3] * e3;
        E += (e0 + e1) + (e2 + e3);
        G += (g0 + g1) + (g2 + g3);
        acc.x += g0 * x0.x + g1 * x1.x + g2 * x2.x + g3 * x3.x;
        acc.y += g0 * x0.y + g1 * x1.y + g2 * x2.y + g3 * x3.y;
        acc.z += g0 * x0.z + g1 * x1.z + g2 * x2.z + g3 * x3.z;
        acc.w += g0 * x0.w + g1 * x1.w + g2 * x2.w + g3 * x3.w;
    }
    accS[w][lane * 4 + 0] = acc.x;
    accS[w][lane * 4 + 1] = acc.y;
    accS[w][lane * 4 + 2] = acc.z;
    accS[w][lane * 4 + 3] = acc.w;
    if (lane == 0) { EGS[w] = E; EGS[4 + w] = G; }
    __syncthreads();
    accp[(size_t)idx * Dsz + tid] = (accS[0][tid] + accS[1][tid]) + (accS[2][tid] + accS[3][tid]);
    if (tid == 0) {
        Ep[idx] = (EGS[0] + EGS[1]) + (EGS[2] + EGS[3]);
        Gp[idx] = (EGS[4] + EGS[5]) + (EGS[6] + EGS[7]);
    }
}

// ---------- kB2: combine, normalize, L = W_V @ xw, epilogue ----------
__global__ __launch_bounds__(256) void kB2(const float* __restrict__ accp,
                                           const float* __restrict__ Ep,
                                           const float* __restrict__ Gp,
                                           const float* __restrict__ WV,
                                           const float* __restrict__ prevL,
                                           const float* __restrict__ prevM,
                                           const float* __restrict__ clsw,
                                           const float* __restrict__ clsb,
                                           float* __restrict__ out) {
    const int b = blockIdx.x;
    const int tid = threadIdx.x;
    const int w = tid >> 6, lane = tid & 63;

    __shared__ float xwS[Dsz];
    __shared__ float red[4];
    __shared__ float red2[4];

    float E = (Ep[b * 4] + Ep[b * 4 + 1]) + (Ep[b * 4 + 2] + Ep[b * 4 + 3]);
    float G = (Gp[b * 4] + Gp[b * 4 + 1]) + (Gp[b * 4 + 2] + Gp[b * 4 + 3]);
    float denom = G + 1e-8f * E;   // softmax shift cancels exactly in this ratio
    float accd = (accp[(size_t)(b * 4 + 0) * Dsz + tid] + accp[(size_t)(b * 4 + 1) * Dsz + tid]) +
                 (accp[(size_t)(b * 4 + 2) * Dsz + tid] + accp[(size_t)(b * 4 + 3) * Dsz + tid]);
    xwS[tid] = (denom > 0.f) ? accd / denom : 0.f;
    __syncthreads();

    float Le = 0.f;
    const float* wvrow = WV + (size_t)tid * Dsz;
    #pragma unroll 4
    for (int d4 = 0; d4 < Dsz; d4 += 4) {
        float4 wv = *(const float4*)(wvrow + d4);
        Le += wv.x * xwS[d4] + wv.y * xwS[d4 + 1] + wv.z * xwS[d4 + 2] + wv.w * xwS[d4 + 3];
    }
    float delta = Le - prevL[(size_t)b * Dsz + tid];

    float ssq = wave_reduce_sum(delta * delta);
    if (lane == 0) red[w] = ssq;
    __syncthreads();
    float nrm = sqrtf((red[0] + red[1]) + (red[2] + red[3]));
    float M = BETA * prevM[b] + (1.f - BETA) * nrm;

    float pp = Le * clsw[tid] + delta * clsw[Dsz + tid];
    float psum = wave_reduce_sum(pp);
    if (lane == 0) red2[w] = psum;
    __syncthreads();

    float* out_p = out;
    float* out_T = out + Bsz;
    float* out_L = out + Bsz + (size_t)Bsz * (2 * Dsz + 1);
    float* out_M = out + Bsz + (size_t)Bsz * (2 * Dsz + 1) + (size_t)Bsz * Dsz;

    out_T[(size_t)b * (2 * Dsz + 1) + tid] = Le;
    out_T[(size_t)b * (2 * Dsz + 1) + Dsz + tid] = delta;
    out_L[(size_t)b * Dsz + tid] = Le;
    if (tid == 0) {
        float p = (red2[0] + red2[1]) + (red2[2] + red2[3]) + M * clsw[2 * Dsz] + clsb[0];
        out_p[b] = p;
        out_T[(size_t)b * (2 * Dsz + 1) + 2 * Dsz] = M;
        out_M[b] = M;
    }
}

extern "C" void kernel_launch(void* const* d_in, const int* in_sizes, int n_in,
                              void* d_out, int out_size, void* d_ws, size_t ws_size,
                              hipStream_t stream) {
    const float* x     = (const float*)d_in[0];
    const float* ts    = (const float*)d_in[1];
    const float* prevL = (const float*)d_in[2];
    const float* prevM = (const float*)d_in[3];
    const unsigned char* pad = (const unsigned char*)d_in[4];
    const float* WQ    = (const float*)d_in[5];
    const float* WK    = (const float*)d_in[6];
    const float* WV    = (const float*)d_in[7];
    const float* clsw  = (const float*)d_in[8];
    const float* clsb  = (const float*)d_in[9];

    float* ws = (float*)d_ws;
    float* qk    = ws;                                   // [B, D]
    float* tmax  = qk + (size_t)Bsz * Dsz;               // [B]
    float* qpart = tmax + Bsz;                           // [B*4, D]
    float* cntp  = qpart + (size_t)Bsz * NCHUNK * Dsz;   // [B*4]
    float* tmaxp = cntp + (size_t)Bsz * NCHUNK;          // [B*4]
    float* accp  = tmaxp + (size_t)Bsz * NCHUNK;         // [B*4, D]
    float* Ep    = accp + (size_t)Bsz * NCHUNK * Dsz;    // [B*4]
    float* Gp    = Ep + (size_t)Bsz * NCHUNK;            // [B*4]

    kA1<<<Bsz * NCHUNK, 256, 0, stream>>>(x, ts, pad, qpart, cntp, tmaxp);
    kA2<<<Bsz, 256, 0, stream>>>(qpart, cntp, tmaxp, WQ, WK, qk, tmax);
    kB1<<<Bsz * NCHUNK, 256, 0, stream>>>(x, ts, pad, qk, tmax, accp, Ep, Gp);
    kB2<<<Bsz, 256, 0, stream>>>(accp, Ep, Gp, WV, prevL, prevM, clsw, clsb, (float*)d_out);
}